// Round 8
// baseline (14228.627 us; speedup 1.0000x reference)
//
#include <hip/hip_runtime.h>

#define T_STEPS 4096
#define N_RES   2048
#define N_IN    64
#define N_OUT   64
#define LEAK    0.3f
#define NOISE_S 0.01f

#define NWG      128     // reservoir WGs
#define RPW      16      // rows per WG
#define RPWAVE   4       // rows per compute wave (= one 16B poll group)
#define NTHREADS 384     // waves 0-3 compute, wave 4 poll, wave 5 writer

typedef unsigned int uint32x4 __attribute__((ext_vector_type(4)));
typedef float        floatx4 __attribute__((ext_vector_type(4)));

// ---------------------------------------------------------------------------
// Kernel 1: it[t][n] = dot(u[t,:], W_in[n,:]) + 0.01*noise[t][n]
// ---------------------------------------------------------------------------
__global__ __launch_bounds__(256) void input_terms_kernel(
    const float* __restrict__ u, const float* __restrict__ noise,
    const float* __restrict__ W_in, float* __restrict__ it) {
  const int t = blockIdx.x;
  const int tid = threadIdx.x;
  __shared__ float su[N_IN];
  if (tid < N_IN) su[tid] = u[(size_t)t * N_IN + tid];
  __syncthreads();
  #pragma unroll
  for (int k = 0; k < N_RES / 256; ++k) {
    const int n = tid + 256 * k;
    const float4* wr = reinterpret_cast<const float4*>(W_in + (size_t)n * N_IN);
    float acc = 0.f;
    #pragma unroll
    for (int j = 0; j < N_IN / 4; ++j) {
      float4 w4 = wr[j];
      acc = fmaf(w4.x, su[4 * j + 0], acc);
      acc = fmaf(w4.y, su[4 * j + 1], acc);
      acc = fmaf(w4.z, su[4 * j + 2], acc);
      acc = fmaf(w4.w, su[4 * j + 3], acc);
    }
    it[(size_t)t * N_RES + n] = acc + NOISE_S * noise[(size_t)t * N_RES + n];
  }
}

// ---------------------------------------------------------------------------
// Kernel 2: persistent recurrence, 4B tagged state, fully specialized waves.
//
// 128 WGs x 384 threads. Waves 0-3: compute — W held in VGPRs (32 float4 per
// thread, loaded via INLINE-ASM global_load_dwordx4 so the compiler cannot
// rematerialize/sink them; R1's C-level loads got sunk, R6's LDS-resident W
// made the compute phase LDS-BW-bound at ~0.8us/step). Their ONLY global op
// per step is lane 0's tagged dwordx4 store. Wave 4: poll-only (no stores
// ever -> its vmcnt(0) covers only its own 8 coalesced poll loads). Wave 5:
// writer — records states[t-1] to it[] from the LDS state buffer (tag-masked
// values, <=3 ulp off) and prefetches it[t+1] into an LDS staging buffer, so
// compute waves touch no HBM.
//
// State word = fp32 bits, low 2 mantissa bits = (step & 3). Producer skew
// <= 2 steps => mod-4 tags disambiguate. s_0 = zeros in LDS, never polled.
// One __syncthreads per step for all 6 waves.
// ---------------------------------------------------------------------------
__global__ __launch_bounds__(NTHREADS, 1) void reservoir_kernel(
    const float* __restrict__ W, float* __restrict__ it,
    unsigned int* sbuf) {
  const int wg = blockIdx.x;
  const int tid = threadIdx.x;
  const int wave = tid >> 6;       // 0..5
  const int lane = tid & 63;
  const int R = wg * RPW;

  __shared__ float ls[2][N_RES];       // 16 KB state double buffer
  __shared__ float stg_it[2][RPW];     // input-term staging (writer -> compute)

  // s_0 = zeros (reset_state=True).
  for (int idx = tid; idx < N_RES; idx += NTHREADS) ls[0][idx] = 0.f;
  if (wave == 5 && lane < RPW) stg_it[0][lane] = it[R + lane];

  if (wave < 4) {
    // ================= compute waves =================
    const int r0 = R + wave * RPWAVE;

    // Preload W rows into VGPRs via inline asm (non-rematerializable).
    // w[8r+j] = W4[r0+r][lane + 64*j]  (matches S4[lane + 64*j]).
    floatx4 w[32];
    #pragma unroll
    for (int r = 0; r < RPWAVE; ++r) {
      const char* p0 = (const char*)(W + (size_t)(r0 + r) * N_RES) + lane * 16;
      const char* p1 = p0 + 4096;
      asm volatile(
          "global_load_dwordx4 %0, %8, off\n\t"
          "global_load_dwordx4 %1, %8, off offset:1024\n\t"
          "global_load_dwordx4 %2, %8, off offset:2048\n\t"
          "global_load_dwordx4 %3, %8, off offset:3072\n\t"
          "global_load_dwordx4 %4, %9, off\n\t"
          "global_load_dwordx4 %5, %9, off offset:1024\n\t"
          "global_load_dwordx4 %6, %9, off offset:2048\n\t"
          "global_load_dwordx4 %7, %9, off offset:3072"
          : "=&v"(w[8 * r + 0]), "=&v"(w[8 * r + 1]),
            "=&v"(w[8 * r + 2]), "=&v"(w[8 * r + 3]),
            "=&v"(w[8 * r + 4]), "=&v"(w[8 * r + 5]),
            "=&v"(w[8 * r + 6]), "=&v"(w[8 * r + 7])
          : "v"(p0), "v"(p1)
          : "memory");
    }
    asm volatile("s_waitcnt vmcnt(0)" ::: "memory");
    __builtin_amdgcn_sched_barrier(0);  // no w-use may be hoisted above
    __syncthreads();  // prologue joins all waves

    for (unsigned int t = 0; t < T_STEPS; ++t) {
      const float* cur = ls[t & 1];
      float* nxt = ls[(t + 1) & 1];
      unsigned int* swb = sbuf + ((t + 1) & 1) * N_RES;

      const floatx4* S4 = reinterpret_cast<const floatx4*>(cur);
      float a0 = 0.f, a1 = 0.f, a2 = 0.f, a3 = 0.f;
      #pragma unroll
      for (int j = 0; j < 8; ++j) {
        const floatx4 s4 = S4[lane + 64 * j];
        const floatx4 x0 = w[j];
        const floatx4 x1 = w[8 + j];
        const floatx4 x2 = w[16 + j];
        const floatx4 x3 = w[24 + j];
        a0 = fmaf(x0.x, s4.x, a0); a0 = fmaf(x0.y, s4.y, a0);
        a0 = fmaf(x0.z, s4.z, a0); a0 = fmaf(x0.w, s4.w, a0);
        a1 = fmaf(x1.x, s4.x, a1); a1 = fmaf(x1.y, s4.y, a1);
        a1 = fmaf(x1.z, s4.z, a1); a1 = fmaf(x1.w, s4.w, a1);
        a2 = fmaf(x2.x, s4.x, a2); a2 = fmaf(x2.y, s4.y, a2);
        a2 = fmaf(x2.z, s4.z, a2); a2 = fmaf(x2.w, s4.w, a2);
        a3 = fmaf(x3.x, s4.x, a3); a3 = fmaf(x3.y, s4.y, a3);
        a3 = fmaf(x3.z, s4.z, a3); a3 = fmaf(x3.w, s4.w, a3);
      }
      #pragma unroll
      for (int off = 32; off > 0; off >>= 1) {
        a0 += __shfl_xor(a0, off);
        a1 += __shfl_xor(a1, off);
        a2 += __shfl_xor(a2, off);
        a3 += __shfl_xor(a3, off);
      }

      const unsigned int tg = (t + 1) & 3u;
      unsigned int pkw = 0;
      if (lane < RPWAVE) {
        const float a = (lane == 0) ? a0 : (lane == 1) ? a1 : (lane == 2) ? a2 : a3;
        const float itv = stg_it[t & 1][wave * RPWAVE + lane];  // staged by wave 5
        const float h = tanhf(itv + a);
        const float sold = cur[r0 + lane];
        const float snew = (1.0f - LEAK) * sold + LEAK * h;
        pkw = (__float_as_uint(snew) & ~3u) | tg;
        // Own value straight into next LDS buffer (bit-identical to what
        // remote WGs read) — wave 4 skips own groups, wave 5 records it.
        nxt[r0 + lane] = __uint_as_float(pkw);
      }
      // Pack 4 rows; lane 0 fires ONE tagged store (fire-and-forget).
      uint32x4 pk;
      pk[0] = __shfl(pkw, 0);
      pk[1] = __shfl(pkw, 1);
      pk[2] = __shfl(pkw, 2);
      pk[3] = __shfl(pkw, 3);
      if (lane == 0) {
        uint32x4* dst = reinterpret_cast<uint32x4*>(swb) + (r0 >> 2);
        asm volatile("global_store_dwordx4 %0, %1, off sc0 sc1"
                     :: "v"(dst), "v"(pk) : "memory");
      }
      __syncthreads();  // nxt complete (own writes + wave-4 remote fills)
    }
  } else if (wave == 4) {
    // ================= poll wave — NEVER stores =================
    __syncthreads();  // prologue join
    unsigned int ownmask = 0;
    {
      const int j = lane - ((wg * 4) & 63);
      if (0 <= j && j < 4) ownmask = 1u << (wg >> 4);
    }
    for (unsigned int t = 0; t < T_STEPS; ++t) {
      if (t + 1 < T_STEPS) {
        unsigned int* swb = sbuf + ((t + 1) & 1) * N_RES;
        float* nxt = ls[(t + 1) & 1];
        const unsigned int tg = (t + 1) & 3u;
        const char* p0 = (const char*)swb + lane * 16;
        const char* p1 = p0 + 4096;
        uint32x4* dst = reinterpret_cast<uint32x4*>(nxt);
        unsigned int need = 0xFFu & ~ownmask;
        for (;;) {
          uint32x4 v0, v1, v2, v3, v4, v5, v6, v7;
          asm volatile(
              "global_load_dwordx4 %0, %8, off sc0 sc1\n\t"
              "global_load_dwordx4 %1, %8, off offset:1024 sc0 sc1\n\t"
              "global_load_dwordx4 %2, %8, off offset:2048 sc0 sc1\n\t"
              "global_load_dwordx4 %3, %8, off offset:3072 sc0 sc1\n\t"
              "global_load_dwordx4 %4, %9, off sc0 sc1\n\t"
              "global_load_dwordx4 %5, %9, off offset:1024 sc0 sc1\n\t"
              "global_load_dwordx4 %6, %9, off offset:2048 sc0 sc1\n\t"
              "global_load_dwordx4 %7, %9, off offset:3072 sc0 sc1\n\t"
              "s_waitcnt vmcnt(0)"
              : "=&v"(v0), "=&v"(v1), "=&v"(v2), "=&v"(v3),
                "=&v"(v4), "=&v"(v5), "=&v"(v6), "=&v"(v7)
              : "v"(p0), "v"(p1)
              : "memory");
          if ((need & 1u)   && ((((v0[0]^tg)|(v0[1]^tg)|(v0[2]^tg)|(v0[3]^tg))&3u)==0u)) { dst[lane +   0] = v0; need &= ~1u; }
          if ((need & 2u)   && ((((v1[0]^tg)|(v1[1]^tg)|(v1[2]^tg)|(v1[3]^tg))&3u)==0u)) { dst[lane +  64] = v1; need &= ~2u; }
          if ((need & 4u)   && ((((v2[0]^tg)|(v2[1]^tg)|(v2[2]^tg)|(v2[3]^tg))&3u)==0u)) { dst[lane + 128] = v2; need &= ~4u; }
          if ((need & 8u)   && ((((v3[0]^tg)|(v3[1]^tg)|(v3[2]^tg)|(v3[3]^tg))&3u)==0u)) { dst[lane + 192] = v3; need &= ~8u; }
          if ((need & 16u)  && ((((v4[0]^tg)|(v4[1]^tg)|(v4[2]^tg)|(v4[3]^tg))&3u)==0u)) { dst[lane + 256] = v4; need &= ~16u; }
          if ((need & 32u)  && ((((v5[0]^tg)|(v5[1]^tg)|(v5[2]^tg)|(v5[3]^tg))&3u)==0u)) { dst[lane + 320] = v5; need &= ~32u; }
          if ((need & 64u)  && ((((v6[0]^tg)|(v6[1]^tg)|(v6[2]^tg)|(v6[3]^tg))&3u)==0u)) { dst[lane + 384] = v6; need &= ~64u; }
          if ((need & 128u) && ((((v7[0]^tg)|(v7[1]^tg)|(v7[2]^tg)|(v7[3]^tg))&3u)==0u)) { dst[lane + 448] = v7; need &= ~128u; }
          if (__all(need == 0u)) break;
          __builtin_amdgcn_s_sleep(1);
        }
      }
      __syncthreads();
    }
  } else {
    // ================= writer wave (wave 5) =================
    // Records states[t-1] from LDS (tag-masked, <=3 ulp) and prefetches
    // it[t+1] into the staging buffer. Keeps ALL HBM ops off compute waves.
    __syncthreads();  // prologue join (stg_it[0] filled above)
    for (unsigned int t = 0; t < T_STEPS; ++t) {
      if (lane < RPW) {
        if (t >= 1)
          it[(size_t)(t - 1) * N_RES + R + lane] = ls[t & 1][R + lane];
        if (t + 1 < T_STEPS)
          stg_it[(t + 1) & 1][lane] = it[(size_t)(t + 1) * N_RES + R + lane];
      }
      __syncthreads();
    }
    if (lane < RPW)  // final state record (ls[0], filled at t = T-1)
      it[(size_t)(T_STEPS - 1) * N_RES + R + lane] = ls[T_STEPS & 1][R + lane];
  }
}

// ---------------------------------------------------------------------------
// Kernel 3: out[t][o] = dot(states[t,:], rw[o,:]) + rb[o]
// ---------------------------------------------------------------------------
__global__ __launch_bounds__(256) void readout_kernel(
    const float* __restrict__ states, const float* __restrict__ rw,
    const float* __restrict__ rb, float* __restrict__ out) {
  const int t = blockIdx.x;
  const int tid = threadIdx.x;
  const int o = tid & 63;
  const int q = tid >> 6;  // 0..3
  __shared__ float ss[N_RES];
  #pragma unroll
  for (int k = 0; k < N_RES / 256; ++k)
    ss[tid + 256 * k] = states[(size_t)t * N_RES + tid + 256 * k];
  __syncthreads();

  const float4* r4 = reinterpret_cast<const float4*>(rw + (size_t)o * N_RES + q * 512);
  float acc = 0.f;
  #pragma unroll 8
  for (int j = 0; j < 128; ++j) {
    float4 w4 = r4[j];
    const int base = q * 512 + 4 * j;
    acc = fmaf(w4.x, ss[base + 0], acc);
    acc = fmaf(w4.y, ss[base + 1], acc);
    acc = fmaf(w4.z, ss[base + 2], acc);
    acc = fmaf(w4.w, ss[base + 3], acc);
  }
  __shared__ float red[256];
  red[tid] = acc;
  __syncthreads();
  if (tid < 64) {
    float v = red[tid] + red[tid + 64] + red[tid + 128] + red[tid + 192];
    out[(size_t)t * N_OUT + tid] = v + rb[tid];
  }
}

// ---------------------------------------------------------------------------
extern "C" void kernel_launch(void* const* d_in, const int* in_sizes, int n_in,
                              void* d_out, int out_size, void* d_ws, size_t ws_size,
                              hipStream_t stream) {
  const float* u     = (const float*)d_in[0];  // [4096, 64]
  const float* noise = (const float*)d_in[1];  // [4096, 2048]
  const float* W_in  = (const float*)d_in[2];  // [2048, 64]
  const float* W     = (const float*)d_in[3];  // [2048, 2048]
  const float* rw    = (const float*)d_in[4];  // [64, 2048]
  const float* rb    = (const float*)d_in[5];  // [64]
  float* out = (float*)d_out;                  // [4096, 64]

  float* it = (float*)d_ws;  // 32 MB: input terms, overwritten with states
  unsigned int* sbuf =
      (unsigned int*)((char*)d_ws + (size_t)T_STEPS * N_RES * sizeof(float));

  // Zero both tagged state buffers every call (0xAA poison would alias tag
  // bits; zeros are safe: stale tag = fresh-2 mod 4, never equal).
  hipMemsetAsync(sbuf, 0, 2 * N_RES * sizeof(unsigned int), stream);

  input_terms_kernel<<<T_STEPS, 256, 0, stream>>>(u, noise, W_in, it);

  void* args[] = {(void*)&W, (void*)&it, (void*)&sbuf};
  hipLaunchCooperativeKernel((void*)reservoir_kernel, dim3(NWG), dim3(NTHREADS),
                             args, 0, stream);

  readout_kernel<<<T_STEPS, 256, 0, stream>>>(it, rw, rb, out);
}